// Round 7
// baseline (256.354 us; speedup 1.0000x reference)
//
#include <hip/hip_runtime.h>
#include <cmath>

// B=16, N=1024, D=512, HEAD=256.  BN = 16384 rows.
#define BN   16384
#define DD   512
#define HEADN 256

typedef unsigned short ushort;
typedef short short8 __attribute__((ext_vector_type(8)));
typedef float floatx4 __attribute__((ext_vector_type(4)));
typedef unsigned short ushort4v __attribute__((ext_vector_type(4)));
typedef unsigned short ushort8v __attribute__((ext_vector_type(8)));

__device__ __forceinline__ ushort f2bf(float v) {
    unsigned int u = __float_as_uint(v);
    unsigned int r = u + 0x7FFFu + ((u >> 16) & 1u);
    return (ushort)(r >> 16);
}
__device__ __forceinline__ float bf2f(ushort u) {
    return __uint_as_float(((unsigned int)u) << 16);
}
// fast tanh: (e^2x - 1)/(e^2x + 1); err ~1e-6 << bf16 ulp
__device__ __forceinline__ float tanh_fast(float x) {
    float xc = fminf(fmaxf(x, -15.0f), 15.0f);
    float e = __expf(2.0f * xc);
    return (e - 1.0f) * __builtin_amdgcn_rcpf(e + 1.0f);
}

// ---------------------------------------------------------------------------
// bf16 MFMA GEMM, tile 128x64, BK=64, 256 threads = 4 waves (R4's verified
// best config: 3-BUFFER LDS + DEPTH-2 PREFETCH, counted vmcnt(6)).
// [Round-17: RANK-STRUCTURE RESTRUCTURE.  mix's h0 = alpha.x + cp(x)P0 +
//  beta(x)Q0 is diagonal+rank-2, so h0@W0 and [h0|hg]@W1 decompose into
//  alpha.(x@W)+cp.(P@W)+beta.(Q@W): h0/hg are NEVER materialized.  x@[W0|W1a]
//  folds into GEMM1 (B extended to N=1536), P@W/Q@W are 16-row micro-GEMMs.
//  Removes: mix_k, mix_k2, GEMM3(4.3GF), GEMM4(6.4GF), Hbuf (~45MB traffic).
//  Adds: G1 N 1024->1536, G_B = g0@W1b (4.3GF), 2 elementwise, 2 micro.]
// Ledger (CPT=6): preload 12 outstanding; top of iter kk waits vmcnt(6) =
// retires exactly tile kk (kk+1 stays IN FLIGHT across the barrier);
// stage(kk+2) re-issues +6.  WAR safe: buf (kk+2)%3=(kk-1)%3 drained by
// lgkmcnt(0)+barrier at top of kk.  Last iter __syncthreads().
// XOR chunk swizzle slot(row,c) = c ^ ((row>>1)&7): ds_read_b128 2-way = free.
// XCD band swizzle: band g&7 owns a contiguous M strip.
// SWAPPED MFMA OPERANDS mfma(bfr, af, acc): lane = (row gr, 4 consecutive
// cols gcb..+3) -> vectorized epilogues.
// Epilogues:
//  EPI 0: float4 store acc + bias[gcb..+3]              -> (float*)Cout, ldc
//  EPI 3: s_arr[gr] += sum_c acc[gr][c] * tcb[gr*tcld+c]  (no store)
//  EPI 5: mixed (G1'): n0<1024 -> bf16 tanh(acc+bias) into Cout ld ldc;
//         n0>=1024 -> raw bf16 acc into gout[gr*512 + gcb-1024]  (Z0 = x@[W0|W1a])
//  EPI 6: raw bf16 store acc -> (ushort*)Cout, ldc       (Zg = g0@W1b)
// ---------------------------------------------------------------------------
template <int TM, int TN, int KK, int EPI>
__global__ __launch_bounds__(256) void gemm_lds(
    const ushort* __restrict__ A, int lda,
    const ushort* __restrict__ Bt,
    const float* __restrict__ bias,
    const ushort* __restrict__ tcb, int tcld,
    float* __restrict__ s_arr,
    void* __restrict__ Cout, int ldc,
    ushort* __restrict__ gout)
{
    constexpr int MI = TM / 32;                 // mfma m-tiles per wave
    constexpr int NI = TN / 32;                 // mfma n-tiles per wave
    constexpr int ROWS = TM + TN;               // staged rows per iter
    constexpr int CPT = (ROWS * 8) / 256;       // 16B chunks per thread (BK=64)
    constexpr int MT = 16384 / TM;
    constexpr int MT_PER_BAND = MT / 8;
    constexpr int NK = KK >> 6;                 // BK = 64
    static_assert(NK >= 2, "need >=2 K-iters for depth-2 pipeline");
    static_assert(CPT == 6, "vmcnt literal below assumes CPT==6");
    __shared__ ushort S[3 * ROWS * 64];         // 3-buffer rotation (72KB)

    const int g = blockIdx.x;
    const int band = g & 7, within = g >> 3;
    const int nt = within / MT_PER_BAND;
    const int mt = band * MT_PER_BAND + (within - nt * MT_PER_BAND);
    const int m0 = mt * TM, n0 = nt * TN;
    const int w = threadIdx.x >> 6, L = threadIdx.x & 63;
    const int wr0 = (w >> 1) * (TM / 2), wc0 = (w & 1) * (TN / 2);
    const int lrow = L & 15, quad = L >> 4;

    // per-thread staging base pointers (computed once; loop adds imm offsets)
    const ushort* gbase[CPT];
#pragma unroll
    for (int rr = 0; rr < CPT; ++rr) {
        const int chunk = rr * 256 + (w << 6) + L;
        const int row = chunk >> 3, slot = chunk & 7;
        const int ca = slot ^ ((row >> 1) & 7);              // swizzled source
        gbase[rr] = (row < TM)
            ? A  + (size_t)(m0 + row) * lda    + (ca << 3)
            : Bt + (size_t)(n0 + row - TM) * KK + (ca << 3);
    }

    floatx4 zero4 = {0.0f, 0.0f, 0.0f, 0.0f};
    floatx4 acc[MI][NI];
#pragma unroll
    for (int i = 0; i < MI; ++i)
#pragma unroll
        for (int j = 0; j < NI; ++j) acc[i][j] = zero4;

    auto stage = [&](int buf, int k0) {
        ushort* Sd = S + buf * (ROWS * 64);
#pragma unroll
        for (int rr = 0; rr < CPT; ++rr) {
            __builtin_amdgcn_global_load_lds(
                (const __attribute__((address_space(1))) unsigned int*)(gbase[rr] + k0),
                (__attribute__((address_space(3))) unsigned int*)(Sd + (rr * 256 + (w << 6)) * 8),
                16, 0, 0);
        }
    };

    stage(0, 0);                                  // preload tiles 0 and 1
    stage(1, 64);
#pragma unroll
    for (int kk = 0; kk < NK; ++kk) {
        // wait: own tile-kk loads retired (tile kk+1 may stay in flight),
        // own ds_reads drained; then barrier -> ALL waves' tile kk landed.
        if (kk + 1 < NK) {
            asm volatile("s_waitcnt vmcnt(6) lgkmcnt(0)" ::: "memory");
            __builtin_amdgcn_s_barrier();
            __builtin_amdgcn_sched_barrier(0);    // pin: no hoist/sink across
        } else {
            __syncthreads();                      // full drain on last iter
        }
        if (kk + 2 < NK) stage((kk + 2) % 3, (kk + 2) << 6);

        const ushort* Sc = S + (kk % 3) * (ROWS * 64);
        short8 af[2][MI], bfr[2][NI];
#pragma unroll
        for (int ks = 0; ks < 2; ++ks) {
#pragma unroll
            for (int mi = 0; mi < MI; ++mi) {
                const int row = wr0 + (mi << 4) + lrow;
                const int slot = ((ks << 2) + quad) ^ ((row >> 1) & 7);
                af[ks][mi] = *(const short8*)(Sc + row * 64 + (slot << 3));
            }
#pragma unroll
            for (int ni = 0; ni < NI; ++ni) {
                const int row = TM + wc0 + (ni << 4) + lrow;
                const int slot = ((ks << 2) + quad) ^ ((row >> 1) & 7);
                bfr[ks][ni] = *(const short8*)(Sc + row * 64 + (slot << 3));
            }
        }
        // SWAPPED operands: D^T in regs -> lane = (row gr, 4 consecutive cols)
#pragma unroll
        for (int ks = 0; ks < 2; ++ks)
#pragma unroll
            for (int mi = 0; mi < MI; ++mi)
#pragma unroll
                for (int ni = 0; ni < NI; ++ni)
                    acc[mi][ni] = __builtin_amdgcn_mfma_f32_16x16x32_bf16(
                        bfr[ks][ni], af[ks][mi], acc[mi][ni], 0, 0, 0);
    }

    // Swapped C/D layout: row gr = ..+lrow, cols gcb..gcb+3, gcb=..+(quad<<2)
    if constexpr (EPI == 3) {
#pragma unroll
        for (int mi = 0; mi < MI; ++mi) {
            const int gr = m0 + wr0 + (mi << 4) + lrow;
            float rs = 0.0f;
#pragma unroll
            for (int ni = 0; ni < NI; ++ni) {
                const int gcb = n0 + wc0 + (ni << 4) + (quad << 2);
                ushort4v t4 = *(const ushort4v*)(tcb + (size_t)gr * tcld + gcb);
#pragma unroll
                for (int p = 0; p < 4; ++p) rs += acc[mi][ni][p] * bf2f(t4[p]);
            }
            rs += __shfl_xor(rs, 16);
            rs += __shfl_xor(rs, 32);
            if (quad == 0) atomicAdd(s_arr + gr, rs);
        }
    } else {
#pragma unroll
        for (int mi = 0; mi < MI; ++mi) {
            const int gr = m0 + wr0 + (mi << 4) + lrow;
#pragma unroll
            for (int ni = 0; ni < NI; ++ni) {
                const int gcb = n0 + wc0 + (ni << 4) + (quad << 2);
                const floatx4 v = acc[mi][ni];
                if constexpr (EPI == 0) {
                    float4 bv = *(const float4*)(bias + gcb);
                    float4 o = {v[0] + bv.x, v[1] + bv.y, v[2] + bv.z, v[3] + bv.w};
                    *(float4*)((float*)Cout + (size_t)gr * ldc + gcb) = o;
                } else if constexpr (EPI == 6) {
                    ushort4v o;
                    o[0] = f2bf(v[0]); o[1] = f2bf(v[1]);
                    o[2] = f2bf(v[2]); o[3] = f2bf(v[3]);
                    *(ushort4v*)((ushort*)Cout + (size_t)gr * ldc + gcb) = o;
                } else {   // EPI == 5
                    if (n0 < 1024) {
                        float4 bv = *(const float4*)(bias + gcb);
                        ushort4v o;
                        o[0] = f2bf(tanh_fast(v[0] + bv.x));
                        o[1] = f2bf(tanh_fast(v[1] + bv.y));
                        o[2] = f2bf(tanh_fast(v[2] + bv.z));
                        o[3] = f2bf(tanh_fast(v[3] + bv.w));
                        *(ushort4v*)((ushort*)Cout + (size_t)gr * ldc + gcb) = o;
                    } else {
                        ushort4v o;
                        o[0] = f2bf(v[0]); o[1] = f2bf(v[1]);
                        o[2] = f2bf(v[2]); o[3] = f2bf(v[3]);
                        *(ushort4v*)(gout + (size_t)gr * 512 + (gcb - 1024)) = o;
                    }
                }
            }
        }
    }
}

// ---------------------------------------------------------------------------
// Prep: blocks [0,4096): xb = bf16(x) + fdot[r] = x[r].fiw  (one wave/row)
//       blocks [4096,5440): weight transposes fp32[K][N] -> bf16[N][K]
//         B1 = [tpwT | tcwT | w0T | w1aT] (1536 x 512, stride 512)
//         bilwT (512x512), owT (512x512), w1bT (256x256, from w1 rows 512:768)
//       block 5440: bias concat
//       blocks [5441,5457): zero the stats region
// ---------------------------------------------------------------------------
__global__ __launch_bounds__(256) void prep_k(
    const float* __restrict__ x, const float* __restrict__ fiw,
    ushort* __restrict__ xb, float* __restrict__ fdot,
    const float* __restrict__ tp_w, const float* __restrict__ tc_w,
    const float* __restrict__ bilw, const float* __restrict__ ow,
    const float* __restrict__ w0, const float* __restrict__ w1,
    const float* __restrict__ tp_b, const float* __restrict__ tc_b,
    ushort* __restrict__ B1, ushort* __restrict__ bilwT,
    ushort* __restrict__ owT, ushort* __restrict__ w1bT,
    float* __restrict__ bias2,
    float* __restrict__ zstats, int zcount)
{
    const int blk0 = blockIdx.x;
    if (blk0 < 4096) {
        const int wv = threadIdx.x >> 6, L = threadIdx.x & 63;
        const int r = (blk0 << 2) + wv;
        const float* xr = x + (size_t)r * DD;
        const int c0 = L << 3;
        float4 v0 = *(const float4*)(xr + c0);
        float4 v1 = *(const float4*)(xr + c0 + 4);
        float4 f0 = *(const float4*)(fiw + c0);
        float4 f1 = *(const float4*)(fiw + c0 + 4);
        float d = v0.x * f0.x + v0.y * f0.y + v0.z * f0.z + v0.w * f0.w
                + v1.x * f1.x + v1.y * f1.y + v1.z * f1.z + v1.w * f1.w;
        ushort8v o;
        o[0] = f2bf(v0.x); o[1] = f2bf(v0.y); o[2] = f2bf(v0.z); o[3] = f2bf(v0.w);
        o[4] = f2bf(v1.x); o[5] = f2bf(v1.y); o[6] = f2bf(v1.z); o[7] = f2bf(v1.w);
        *(ushort8v*)(xb + (size_t)r * DD + c0) = o;
#pragma unroll
        for (int off = 32; off > 0; off >>= 1) d += __shfl_xor(d, off);
        if (L == 0) fdot[r] = d;
        return;
    }
    if (blk0 >= 5441) {                       // zero stats region
        for (int i = (blk0 - 5441) * 256 + threadIdx.x; i < zcount; i += 16 * 256)
            zstats[i] = 0.0f;
        return;
    }
    const int blk = blk0 - 4096;
    if (blk >= 1344) {
        for (int i = threadIdx.x; i < 512; i += 256) {
            bias2[i] = tp_b[i];
            bias2[512 + i] = tc_b[i];
        }
        return;
    }
    const float* W; ushort* Wt; int K, N, local;
    if (blk < 256)       { W = tp_w;           Wt = B1;              K = 512; N = 512; local = blk; }
    else if (blk < 512)  { W = tc_w;           Wt = B1 + 512 * 512;  K = 512; N = 512; local = blk - 256; }
    else if (blk < 768)  { W = bilw;           Wt = bilwT;           K = 512; N = 512; local = blk - 512; }
    else if (blk < 1024) { W = ow;             Wt = owT;             K = 512; N = 512; local = blk - 768; }
    else if (blk < 1152) { W = w0;             Wt = B1 + 1024 * 512; K = 512; N = 256; local = blk - 1024; }
    else if (blk < 1280) { W = w1;             Wt = B1 + 1280 * 512; K = 512; N = 256; local = blk - 1152; }  // w1a
    else                 { W = w1 + 512 * 256; Wt = w1bT;            K = 256; N = 256; local = blk - 1280; }  // w1b

    __shared__ float t[32][33];
    const int nb = N >> 5;
    const int kb = local / nb, nbb = local % nb;
    const int k0 = kb << 5, n0 = nbb << 5;
    const int c = threadIdx.x & 31, r = threadIdx.x >> 5;   // r 0..7
#pragma unroll
    for (int i = 0; i < 4; ++i)
        t[r + 8 * i][c] = W[(size_t)(k0 + r + 8 * i) * N + n0 + c];
    __syncthreads();
#pragma unroll
    for (int i = 0; i < 4; ++i)
        Wt[(size_t)(n0 + r + 8 * i) * K + k0 + c] = f2bf(t[c][r + 8 * i]);
}

// ---------------------------------------------------------------------------
// Layer-0 PQ + fused finalize: a=exp(s), f=exp(fdot) computed on the fly
// (written once per row from c4==0 lanes; block-partial S,H -> atomics),
// P0[c]=sum a_n V[n,c], Q0[c]=sum a_n f_n V[n,c].  V = xb (C=512).
// grid = 16 batches x 16 row-chunks(64).
// ---------------------------------------------------------------------------
__global__ __launch_bounds__(256) void batch_pq_f(
    const ushort* __restrict__ V, const float* __restrict__ s_arr,
    const float* __restrict__ fdot,
    float* __restrict__ a, float* __restrict__ f,
    float* __restrict__ P, float* __restrict__ Q,
    float* __restrict__ Sb, float* __restrict__ Hb, int C)
{
    __shared__ float redP[256][4];
    __shared__ float redQ[256][4];
    __shared__ float sSh[4], sHh[4];
    const int b = blockIdx.x >> 4;
    const int chunk = blockIdx.x & 15;
    const int c4cnt = C >> 2;
    const int rg = 256 / c4cnt;
    const int c4 = threadIdx.x & (c4cnt - 1);
    const int sub = threadIdx.x / c4cnt;
    const ushort* Vb = V + (size_t)b * 1024 * C;
    const float* sB = s_arr + (b << 10);
    const float* fB = fdot + (b << 10);
    const int n0 = chunk << 6;
    float4 p = {0, 0, 0, 0}, q = {0, 0, 0, 0};
    float sS = 0.f, sH = 0.f;
    for (int n = n0 + sub; n < n0 + 64; n += rg) {
        const float av = __expf(sB[n]);
        const float fv = __expf(fB[n]);
        const float afv = av * fv;
        if (c4 == 0) {
            a[(b << 10) + n] = av;
            f[(b << 10) + n] = fv;
            sS += av; sH += afv;
        }
        ushort4v u = *(const ushort4v*)(Vb + (size_t)n * C + (c4 << 2));
        float4 v = {bf2f(u[0]), bf2f(u[1]), bf2f(u[2]), bf2f(u[3])};
        p.x += av * v.x; p.y += av * v.y; p.z += av * v.z; p.w += av * v.w;
        q.x += afv * v.x; q.y += afv * v.y; q.z += afv * v.z; q.w += afv * v.w;
    }
    if (c4 == 0) { sSh[sub] = sS; sHh[sub] = sH; }
    redP[threadIdx.x][0] = p.x; redP[threadIdx.x][1] = p.y;
    redP[threadIdx.x][2] = p.z; redP[threadIdx.x][3] = p.w;
    redQ[threadIdx.x][0] = q.x; redQ[threadIdx.x][1] = q.y;
    redQ[threadIdx.x][2] = q.z; redQ[threadIdx.x][3] = q.w;
    __syncthreads();
    if (threadIdx.x == 0) {
        float tS = 0.f, tH = 0.f;
        for (int s = 0; s < rg; ++s) { tS += sSh[s]; tH += sHh[s]; }
        atomicAdd(Sb + b, tS);
        atomicAdd(Hb + b, tH);
    }
    if (sub == 0) {
        for (int s = 1; s < rg; ++s) {
            const int t2 = threadIdx.x + s * c4cnt;
            p.x += redP[t2][0]; p.y += redP[t2][1]; p.z += redP[t2][2]; p.w += redP[t2][3];
            q.x += redQ[t2][0]; q.y += redQ[t2][1]; q.z += redQ[t2][2]; q.w += redQ[t2][3];
        }
        float* Pp = P + b * C + (c4 << 2);
        float* Qp = Q + b * C + (c4 << 2);
        atomicAdd(Pp + 0, p.x); atomicAdd(Pp + 1, p.y);
        atomicAdd(Pp + 2, p.z); atomicAdd(Pp + 3, p.w);
        atomicAdd(Qp + 0, q.x); atomicAdd(Qp + 1, q.y);
        atomicAdd(Qp + 2, q.z); atomicAdd(Qp + 3, q.w);
    }
}

// ---------------------------------------------------------------------------
// PW/QW = [P0;Q0] @ [W0 | W1a]  (fp32, exact).  64 blocks x 256 thr, 1 dot
// of 512 each.  Layout PW[16][512]: cols 0:256 = @W0, 256:512 = @W1a.
// ---------------------------------------------------------------------------
__global__ __launch_bounds__(256) void pqw0_k(
    const float* __restrict__ P0, const float* __restrict__ Q0,
    const float* __restrict__ w0, const float* __restrict__ w1,
    float* __restrict__ PW, float* __restrict__ QW)
{
    const int bi = blockIdx.x;            // 64
    const int which = bi >> 5;            // 0:P 1:Q
    const int rem = bi & 31;
    const int b = rem >> 1, half = rem & 1;
    const int c = threadIdx.x;            // 0..255
    const float* src = (which ? Q0 : P0) + b * 512;
    const float* Wm = half ? w1 : w0;     // both [k][256], k rows 0:512
    float acc = 0.f;
    for (int k = 0; k < 512; ++k) acc += src[k] * Wm[k * 256 + c];
    float* dst = (which ? QW : PW) + b * 512 + half * 256 + c;
    *dst = acc;
}

// PW1/QW1 = [P1;Q1] @ W1b  (w1 rows 512:768).  32 blocks.
__global__ __launch_bounds__(256) void pqw1_k(
    const float* __restrict__ P1, const float* __restrict__ Q1,
    const float* __restrict__ w1,
    float* __restrict__ PW1, float* __restrict__ QW1)
{
    const int bi = blockIdx.x;            // 32
    const int which = bi >> 4, b = bi & 15;
    const int c = threadIdx.x;
    const float* src = (which ? Q1 : P1) + b * 256;
    float acc = 0.f;
    for (int k = 0; k < 256; ++k) acc += src[k] * w1[(size_t)(512 + k) * 256 + c];
    ((which ? QW1 : PW1) + b * 256)[c] = acc;
}

// ---------------------------------------------------------------------------
// ew0: g0 = relu((alpha.Z0[:, :256] + cp.PW0 + beta.QW0 + 2 b0) / den)
// (h0@W0 via rank decomposition; h0 never materialized).  Writes g0b bf16,
// gcnb[:,0:256] = bf16(g0 + xb[:,0:256]); fused P1/Q1 += a (.f) g0 sums.
// grid = 256 blocks x 64 rows; thread = (sub rows, c4 cols).
// ---------------------------------------------------------------------------
__global__ __launch_bounds__(256) void ew0_k(
    const ushort* __restrict__ Z0, const ushort* __restrict__ xb,
    ushort* __restrict__ g0b, ushort* __restrict__ gcnb,
    const float* __restrict__ a, const float* __restrict__ f,
    const float* __restrict__ Sb, const float* __restrict__ Hb,
    const float* __restrict__ PW, const float* __restrict__ QW,
    const float* __restrict__ b0,
    float* __restrict__ P1, float* __restrict__ Q1)
{
    __shared__ float redP[4][64][4];
    __shared__ float redQ[4][64][4];
    const int blk = blockIdx.x;          // 256 blocks x 64 rows
    const int r0 = blk << 6;
    const int b = r0 >> 10;
    const int c4 = threadIdx.x & 63;
    const int sub = threadIdx.x >> 6;
    const int c = c4 << 2;
    const float S = Sb[b], H = Hb[b];
    const float rS = __builtin_amdgcn_rcpf(S);
    const float rH = __builtin_amdgcn_rcpf(H);
    float4 bv = *(const float4*)(b0 + c);
    float4 pw = *(const float4*)(PW + b * 512 + c);
    float4 qw = *(const float4*)(QW + b * 512 + c);
    float sP[4] = {0.f, 0.f, 0.f, 0.f}, sQ[4] = {0.f, 0.f, 0.f, 0.f};
    for (int rr = 0; rr < 16; ++rr) {
        const int r = r0 + (sub << 4) + rr;
        const float av = a[r], fv = f[r];
        const float alpha = 1.0f - av * rS;
        const float beta = av * rS * rH;
        const float cpv = rS - beta * fv;
        const float rdv = __builtin_amdgcn_rcpf(2.0f - av * fv * rH);
        ushort4v z  = *(const ushort4v*)(Z0 + (size_t)r * 512 + c);
        ushort4v xg = *(const ushort4v*)(xb + (size_t)r * 512 + c);
        ushort4v og, oc;
        float u;
        u = (alpha * bf2f(z[0]) + cpv * pw.x + beta * qw.x + 2.0f * bv.x) * rdv;
        u = u > 0.f ? u : 0.f; og[0] = f2bf(u); oc[0] = f2bf(u + bf2f(xg[0]));
        sP[0] += av * u; sQ[0] += av * fv * u;
        u = (alpha * bf2f(z[1]) + cpv * pw.y + beta * qw.y + 2.0f * bv.y) * rdv;
        u = u > 0.f ? u : 0.f; og[1] = f2bf(u); oc[1] = f2bf(u + bf2f(xg[1]));
        sP[1] += av * u; sQ[1] += av * fv * u;
        u = (alpha * bf2f(z[2]) + cpv * pw.z + beta * qw.z + 2.0f * bv.z) * rdv;
        u = u > 0.f ? u : 0.f; og[2] = f2bf(u); oc[2] = f2bf(u + bf2f(xg[2]));
        sP[2] += av * u; sQ[2] += av * fv * u;
        u = (alpha * bf2f(z[3]) + cpv * pw.w + beta * qw.w + 2.0f * bv.w) * rdv;
        u = u > 0.f ? u : 0.f; og[3] = f2bf(u); oc[3] = f2bf(u + bf2f(xg[3]));
        sP[3] += av * u; sQ[3] += av * fv * u;
        *(ushort4v*)(g0b  + (size_t)r * 256 + c) = og;
        *(ushort4v*)(gcnb + (size_t)r * 512 + c) = oc;
    }
#pragma unroll
    for (int p = 0; p < 4; ++p) { redP[sub][c4][p] = sP[p]; redQ[sub][c4][p] = sQ[p]; }
    __syncthreads();
    if (sub == 0) {
#pragma unroll
        for (int p = 0; p < 4; ++p) {
            float vP = redP[0][c4][p] + redP[1][c4][p] + redP[2][c4][p] + redP[3][c4][p];
            float vQ = redQ[0][c4][p] + redQ[1][c4][p] + redQ[2][c4][p] + redQ[3][c4][p];
            atomicAdd(P1 + b * 256 + c + p, vP);
            atomicAdd(Q1 + b * 256 + c + p, vQ);
        }
    }
}

// ---------------------------------------------------------------------------
// ew1: g1 = relu((alpha.(Z0[:,256:512]+Zg) + cp.(PW[:,256:]+PW1)
//               + beta.(QW[:,256:]+QW1) + 2 b1) / den);
// gcnb[:,256:512] = bf16(g1 + xb[:,256:512]).  ([h0|hg]@W1 decomposed.)
// ---------------------------------------------------------------------------
__global__ __launch_bounds__(256) void ew1_k(
    const ushort* __restrict__ Z0, const ushort* __restrict__ Zg,
    const ushort* __restrict__ xb, ushort* __restrict__ gcnb,
    const float* __restrict__ a, const float* __restrict__ f,
    const float* __restrict__ Sb, const float* __restrict__ Hb,
    const float* __restrict__ PW, const float* __restrict__ QW,
    const float* __restrict__ PW1, const float* __restrict__ QW1,
    const float* __restrict__ b1)
{
    const int idx = blockIdx.x * 256 + threadIdx.x;   // 16384*64
    const int c4 = idx & 63, r = idx >> 6;
    const int b = r >> 10;
    const int c = c4 << 2;
    const float av = a[r], fv = f[r], S = Sb[b], H = Hb[b];
    const float rS = __builtin_amdgcn_rcpf(S);
    const float rH = __builtin_amdgcn_rcpf(H);
    const float alpha = 1.0f - av * rS;
    const float beta = av * rS * rH;
    const float cpv = rS - beta * fv;
    const float rdv = __builtin_amdgcn_rcpf(2.0f - av * fv * rH);
    float4 bv = *(const float4*)(b1 + c);
    float4 pwa = *(const float4*)(PW + b * 512 + 256 + c);
    float4 qwa = *(const float4*)(QW + b * 512 + 256 + c);
    float4 pw1 = *(const float4*)(PW1 + b * 256 + c);
    float4 qw1 = *(const float4*)(QW1 + b * 256 + c);
    ushort4v za = *(const ushort4v*)(Z0 + (size_t)r * 512 + 256 + c);
    ushort4v zg = *(const ushort4v*)(Zg + (size_t)r * 256 + c);
    ushort4v xg = *(const ushort4v*)(xb + (size_t)r * 512 + 256 + c);
    ushort4v o;
    float u;
    u = (alpha * (bf2f(za[0]) + bf2f(zg[0])) + cpv * (pwa.x + pw1.x)
       + beta * (qwa.x + qw1.x) + 2.0f * bv.x) * rdv;
    u = u > 0.f ? u : 0.f; o[0] = f2bf(u + bf2f(xg[0]));
    u = (alpha * (bf2f(za[1]) + bf2f(zg[1])) + cpv * (pwa.y + pw1.y)
       + beta * (qwa.y + qw1.y) + 2.0f * bv.y) * rdv;
    u = u > 0.f ? u : 0.f; o[1] = f2bf(u + bf2f(xg[1]));
    u = (alpha * (bf2f(za[2]) + bf2f(zg[2])) + cpv * (pwa.z + pw1.z)
       + beta * (qwa.z + qw1.z) + 2.0f * bv.z) * rdv;
    u = u > 0.f ? u : 0.f; o[2] = f2bf(u + bf2f(xg[2]));
    u = (alpha * (bf2f(za[3]) + bf2f(zg[3])) + cpv * (pwa.w + pw1.w)
       + beta * (qwa.w + qw1.w) + 2.0f * bv.w) * rdv;
    u = u > 0.f ? u : 0.f; o[3] = f2bf(u + bf2f(xg[3]));
    *(ushort4v*)(gcnb + (size_t)r * 512 + 256 + c) = o;
}

extern "C" void kernel_launch(void* const* d_in, const int* in_sizes, int n_in,
                              void* d_out, int out_size, void* d_ws, size_t ws_size,
                              hipStream_t stream)
{
    (void)in_sizes; (void)n_in; (void)out_size; (void)ws_size;
    const float* x    = (const float*)d_in[0];
    const float* tp_w = (const float*)d_in[1];
    const float* tp_b = (const float*)d_in[2];
    const float* tc_w = (const float*)d_in[3];
    const float* tc_b = (const float*)d_in[4];
    const float* fi_w = (const float*)d_in[5];
    const float* bilw = (const float*)d_in[6];
    const float* w0   = (const float*)d_in[7];
    const float* b0   = (const float*)d_in[8];
    const float* w1   = (const float*)d_in[9];
    const float* b1   = (const float*)d_in[10];
    const float* ow   = (const float*)d_in[11];
    const float* ob   = (const float*)d_in[12];

    char* W = (char*)d_ws;
    ushort* xb    = (ushort*)W;                          // [0,16M)  xb -> gcnb overlay
    ushort* gcnb  = xb;
    ushort* tptcb = (ushort*)(W + ((size_t)16 << 20));   // [16M,48M) 32MB [tp|tc]
    ushort* Z0b   = (ushort*)(W + ((size_t)48 << 20));   // [48M,64M) 16MB x@[W0|W1a]
    ushort* g0b   = (ushort*)(W + ((size_t)64 << 20));   // [64M,72M) 8MB
    ushort* Zgb   = (ushort*)(W + ((size_t)72 << 20));   // [72M,80M) 8MB g0@W1b
    ushort* B1    = (ushort*)(W + ((size_t)80 << 20));   // 1536x512 bf16
    ushort* bilwT = B1 + 1536 * 512;                     // 512x512
    ushort* owT   = bilwT + 262144;                      // 512x512
    ushort* w1bT  = owT + 262144;                        // 256x256
    float*  bias2 = (float*)(w1bT + 65536);              // 1024 floats
    float* stats  = (float*)(W + ((size_t)84 << 20));
    // contiguous zero region: s_arr,P0,Q0,P1,Q1,Sb,Hb = 40992 floats
    float* s_arr  = stats;             // 16384
    float* P0     = s_arr + 16384;     // 8192
    float* Q0     = P0 + 8192;         // 8192
    float* P1     = Q0 + 8192;         // 4096
    float* Q1     = P1 + 4096;         // 4096
    float* Sb     = Q1 + 4096;         // 16
    float* Hb     = Sb + 16;           // 16
    const int zcount = 16384 + 2 * 8192 + 2 * 4096 + 32;
    float* fdot   = Hb + 16;           // 16384
    float* arr_a  = fdot + BN;         // 16384
    float* arr_f  = arr_a + BN;        // 16384
    float* PW     = arr_f + BN;        // 16x512
    float* QW     = PW + 8192;         // 16x512
    float* PW1    = QW + 8192;         // 16x256
    float* QW1    = PW1 + 4096;        // 16x256

    // prep: xb=bf16(x), fdot, weight transposes, bias concat, stats zeroing
    prep_k<<<5457, 256, 0, stream>>>(x, fi_w, xb, fdot, tp_w, tc_w, bilw, ow, w0, w1,
                                     tp_b, tc_b, B1, bilwT, owT, w1bT, bias2,
                                     s_arr, zcount);
    // G1': [tp|tc] = tanh(x@[tpw|tcw]+bias) AND Z0 = x@[W0|W1a]  (N=1536)
    // grid = 128 * (1536/64) = 3072 blocks
    gemm_lds<128, 64, 512, 5><<<3072, 256, 0, stream>>>(xb, 512, B1, bias2,
        nullptr, 0, nullptr, tptcb, 1024, Z0b);
    // G2: s[r] = (tp@bilw)[r] . tc[r]
    gemm_lds<128, 64, 512, 3><<<1024, 256, 0, stream>>>(tptcb, 1024, bilwT, nullptr,
        tptcb + 512, 1024, s_arr, nullptr, 0, nullptr);
    // layer 0 PQ + fused finalize: a, f, S, H, P0, Q0
    batch_pq_f<<<256, 256, 0, stream>>>(xb, s_arr, fdot, arr_a, arr_f,
                                        P0, Q0, Sb, Hb, 512);
    // micro: PW/QW = [P0;Q0]@[W0|W1a] (fp32 exact)
    pqw0_k<<<64, 256, 0, stream>>>(P0, Q0, w0, w1, PW, QW);
    // ew0: g0 + gcnb[:,0:256] + fused P1/Q1 accumulation
    ew0_k<<<256, 256, 0, stream>>>(Z0b, xb, g0b, gcnb, arr_a, arr_f, Sb, Hb,
                                   PW, QW, b0, P1, Q1);
    // G_B: Zg = g0@W1b  (raw bf16)
    gemm_lds<128, 64, 256, 6><<<512, 256, 0, stream>>>(g0b, 256, w1bT, nullptr,
        nullptr, 0, nullptr, Zgb, 256, nullptr);
    // micro: PW1/QW1 = [P1;Q1]@W1b
    pqw1_k<<<32, 256, 0, stream>>>(P1, Q1, w1, PW1, QW1);
    // ew1: g1 + gcnb[:,256:512]
    ew1_k<<<4096, 256, 0, stream>>>(Z0b, Zgb, xb, gcnb, arr_a, arr_f, Sb, Hb,
                                    PW, QW, PW1, QW1, b1);
    // out = gcn@out_w + out_b  (fp32)
    gemm_lds<128, 64, 512, 0><<<1024, 256, 0, stream>>>(gcnb, 512, owT, ob,
        nullptr, 0, nullptr, (float*)d_out, 512, nullptr);
}

// Round 8
// 225.437 us; speedup vs baseline: 1.1371x; 1.1371x over previous
//
#include <hip/hip_runtime.h>
#include <cmath>

// B=16, N=1024, D=512, HEAD=256.  BN = 16384 rows.
#define BN   16384
#define DD   512
#define HEADN 256

typedef unsigned short ushort;
typedef short short8 __attribute__((ext_vector_type(8)));
typedef float floatx4 __attribute__((ext_vector_type(4)));
typedef unsigned short ushort4v __attribute__((ext_vector_type(4)));
typedef unsigned short ushort8v __attribute__((ext_vector_type(8)));

__device__ __forceinline__ ushort f2bf(float v) {
    unsigned int u = __float_as_uint(v);
    unsigned int r = u + 0x7FFFu + ((u >> 16) & 1u);
    return (ushort)(r >> 16);
}
__device__ __forceinline__ float bf2f(ushort u) {
    return __uint_as_float(((unsigned int)u) << 16);
}
// fast tanh: (e^2x - 1)/(e^2x + 1); err ~1e-6 << bf16 ulp
__device__ __forceinline__ float tanh_fast(float x) {
    float xc = fminf(fmaxf(x, -15.0f), 15.0f);
    float e = __expf(2.0f * xc);
    return (e - 1.0f) * __builtin_amdgcn_rcpf(e + 1.0f);
}

// ---------------------------------------------------------------------------
// [Round-18] Chain reverted to R4 champion (230.8us).  R7 counters finally
// exposed the GEMM regime: MfmaUtil 19 / VALU 26 / HBM 16 / Occ 18, 0 bank
// conflicts -> serialization-bound (ds_read latency + barrier + vmcnt waits
// with only 2 waves/SIMD), not pipe-bound.  Fix = T3-style 2-PHASE schedule
// on the three big GEMMs (G1/G2/G5, 83% of GEMM FLOPs), gemm2p below:
//   tile 128x128 (2x MFMA per staged byte), 2-buffer LDS 64KB (2 blk/CU),
//   per K-iter: {vmcnt(8)+lgkm(0); barrier; 16x ds_read_b128 -> regs;
//   lgkm(0); barrier; stage(kk+2 -> just-consumed buf); setprio(1);
//   32 pure-reg MFMA; setprio(0)}.  Counted vmcnt NEVER 0 in steady state.
//   WAR-safe: all waves' ds_reads of buf drained (lgkm0+barrier) before any
//   wave's stage overwrites it; tile kk+1 stays in flight across barriers.
// G3/G4 (N=256) keep the verified R4 128x64 3-buffer kernel (grid 512;
// a 128-wide N-tile would halve their block count).
// Common: XOR chunk swizzle slot = c ^ ((row>>1)&7) (2-way = free);
// XCD band swizzle; SWAPPED MFMA operands -> lane = (row gr, 4 consecutive
// cols) -> vectorized epilogues.  Per-output K-order unchanged -> bitwise-
// identical results (absmax canary 0.08203125).
// Epilogues (acc[mi][ni][p] = C[gr][gcb+p]):
//  EPI 0: float4 store acc + bias[gcb..+3]              -> (float*)Cout, ldc
//  EPI 1: 8B bf16 store tanh_fast(acc + bias)           -> (ushort*)Cout, ldc
//  EPI 2: u = relu((acc + 2*bias) * rcp(denom[gr]));
//         if Cout: 8B bf16 store u; if gout: gout[gr*512+xoff+gcb..] = u+xgb
//  EPI 3: s_arr[gr] += sum_c acc[gr][c] * tcb[gr*tcld+c]  (no store)
// ---------------------------------------------------------------------------
template <int TM, int TN, int KK, int EPI>
__global__ __launch_bounds__(256) void gemm_lds(
    const ushort* __restrict__ A, int lda,
    const ushort* __restrict__ Bt, int N,
    const float* __restrict__ bias,
    const float* __restrict__ denom,
    const ushort* __restrict__ tcb, int tcld,
    float* __restrict__ s_arr,
    void* __restrict__ Cout, int ldc,
    const ushort* __restrict__ xgb, int xoff, ushort* __restrict__ gout)
{
    constexpr int MI = TM / 32;
    constexpr int NI = TN / 32;
    constexpr int ROWS = TM + TN;
    constexpr int CPT = (ROWS * 8) / 256;
    constexpr int MT = 16384 / TM;
    constexpr int MT_PER_BAND = MT / 8;
    constexpr int NK = KK >> 6;
    static_assert(NK >= 2, "need >=2 K-iters for depth-2 pipeline");
    static_assert(CPT == 6, "vmcnt literal below assumes CPT==6");
    __shared__ ushort S[3 * ROWS * 64];         // 3-buffer rotation (72KB)

    const int g = blockIdx.x;
    const int band = g & 7, within = g >> 3;
    const int nt = within / MT_PER_BAND;
    const int mt = band * MT_PER_BAND + (within - nt * MT_PER_BAND);
    const int m0 = mt * TM, n0 = nt * TN;
    const int w = threadIdx.x >> 6, L = threadIdx.x & 63;
    const int wr0 = (w >> 1) * (TM / 2), wc0 = (w & 1) * (TN / 2);
    const int lrow = L & 15, quad = L >> 4;

    const ushort* gbase[CPT];
#pragma unroll
    for (int rr = 0; rr < CPT; ++rr) {
        const int chunk = rr * 256 + (w << 6) + L;
        const int row = chunk >> 3, slot = chunk & 7;
        const int ca = slot ^ ((row >> 1) & 7);
        gbase[rr] = (row < TM)
            ? A  + (size_t)(m0 + row) * lda    + (ca << 3)
            : Bt + (size_t)(n0 + row - TM) * KK + (ca << 3);
    }

    floatx4 zero4 = {0.0f, 0.0f, 0.0f, 0.0f};
    floatx4 acc[MI][NI];
#pragma unroll
    for (int i = 0; i < MI; ++i)
#pragma unroll
        for (int j = 0; j < NI; ++j) acc[i][j] = zero4;

    auto stage = [&](int buf, int k0) {
        ushort* Sd = S + buf * (ROWS * 64);
#pragma unroll
        for (int rr = 0; rr < CPT; ++rr) {
            __builtin_amdgcn_global_load_lds(
                (const __attribute__((address_space(1))) unsigned int*)(gbase[rr] + k0),
                (__attribute__((address_space(3))) unsigned int*)(Sd + (rr * 256 + (w << 6)) * 8),
                16, 0, 0);
        }
    };

    stage(0, 0);
    stage(1, 64);
#pragma unroll
    for (int kk = 0; kk < NK; ++kk) {
        if (kk + 1 < NK) {
            asm volatile("s_waitcnt vmcnt(6) lgkmcnt(0)" ::: "memory");
            __builtin_amdgcn_s_barrier();
            __builtin_amdgcn_sched_barrier(0);
        } else {
            __syncthreads();
        }
        if (kk + 2 < NK) stage((kk + 2) % 3, (kk + 2) << 6);

        const ushort* Sc = S + (kk % 3) * (ROWS * 64);
        short8 af[2][MI], bfr[2][NI];
#pragma unroll
        for (int ks = 0; ks < 2; ++ks) {
#pragma unroll
            for (int mi = 0; mi < MI; ++mi) {
                const int row = wr0 + (mi << 4) + lrow;
                const int slot = ((ks << 2) + quad) ^ ((row >> 1) & 7);
                af[ks][mi] = *(const short8*)(Sc + row * 64 + (slot << 3));
            }
#pragma unroll
            for (int ni = 0; ni < NI; ++ni) {
                const int row = TM + wc0 + (ni << 4) + lrow;
                const int slot = ((ks << 2) + quad) ^ ((row >> 1) & 7);
                bfr[ks][ni] = *(const short8*)(Sc + row * 64 + (slot << 3));
            }
        }
#pragma unroll
        for (int ks = 0; ks < 2; ++ks)
#pragma unroll
            for (int mi = 0; mi < MI; ++mi)
#pragma unroll
                for (int ni = 0; ni < NI; ++ni)
                    acc[mi][ni] = __builtin_amdgcn_mfma_f32_16x16x32_bf16(
                        bfr[ks][ni], af[ks][mi], acc[mi][ni], 0, 0, 0);
    }

    if constexpr (EPI == 3) {
#pragma unroll
        for (int mi = 0; mi < MI; ++mi) {
            const int gr = m0 + wr0 + (mi << 4) + lrow;
            float rs = 0.0f;
#pragma unroll
            for (int ni = 0; ni < NI; ++ni) {
                const int gcb = n0 + wc0 + (ni << 4) + (quad << 2);
                ushort4v t4 = *(const ushort4v*)(tcb + (size_t)gr * tcld + gcb);
#pragma unroll
                for (int p = 0; p < 4; ++p) rs += acc[mi][ni][p] * bf2f(t4[p]);
            }
            rs += __shfl_xor(rs, 16);
            rs += __shfl_xor(rs, 32);
            if (quad == 0) atomicAdd(s_arr + gr, rs);
        }
    } else {
#pragma unroll
        for (int mi = 0; mi < MI; ++mi) {
            const int gr = m0 + wr0 + (mi << 4) + lrow;
            const float rdv = (EPI == 2) ? __builtin_amdgcn_rcpf(denom[gr]) : 1.0f;
#pragma unroll
            for (int ni = 0; ni < NI; ++ni) {
                const int gcb = n0 + wc0 + (ni << 4) + (quad << 2);
                const floatx4 v = acc[mi][ni];
                if constexpr (EPI == 0) {
                    float4 bv = *(const float4*)(bias + gcb);
                    float4 o = {v[0] + bv.x, v[1] + bv.y, v[2] + bv.z, v[3] + bv.w};
                    *(float4*)((float*)Cout + (size_t)gr * ldc + gcb) = o;
                } else if constexpr (EPI == 1) {
                    float4 bv = *(const float4*)(bias + gcb);
                    ushort4v o;
                    o[0] = f2bf(tanh_fast(v[0] + bv.x));
                    o[1] = f2bf(tanh_fast(v[1] + bv.y));
                    o[2] = f2bf(tanh_fast(v[2] + bv.z));
                    o[3] = f2bf(tanh_fast(v[3] + bv.w));
                    *(ushort4v*)((ushort*)Cout + (size_t)gr * ldc + gcb) = o;
                } else {
                    float4 bv = *(const float4*)(bias + gcb);
                    float u0 = (v[0] + 2.0f * bv.x) * rdv; u0 = u0 > 0.0f ? u0 : 0.0f;
                    float u1 = (v[1] + 2.0f * bv.y) * rdv; u1 = u1 > 0.0f ? u1 : 0.0f;
                    float u2 = (v[2] + 2.0f * bv.z) * rdv; u2 = u2 > 0.0f ? u2 : 0.0f;
                    float u3 = (v[3] + 2.0f * bv.w) * rdv; u3 = u3 > 0.0f ? u3 : 0.0f;
                    if (Cout) {
                        ushort4v o;
                        o[0] = f2bf(u0); o[1] = f2bf(u1); o[2] = f2bf(u2); o[3] = f2bf(u3);
                        *(ushort4v*)((ushort*)Cout + (size_t)gr * ldc + gcb) = o;
                    }
                    if (gout) {
                        const size_t gb = (size_t)gr * 512 + xoff + gcb;
                        ushort4v xg = *(const ushort4v*)(xgb + gb);
                        ushort4v o;
                        o[0] = f2bf(u0 + bf2f(xg[0]));
                        o[1] = f2bf(u1 + bf2f(xg[1]));
                        o[2] = f2bf(u2 + bf2f(xg[2]));
                        o[3] = f2bf(u3 + bf2f(xg[3]));
                        *(ushort4v*)(gout + gb) = o;
                    }
                }
            }
        }
    }
}

// ---------------------------------------------------------------------------
// gemm2p: 128x128-tile 2-PHASE GEMM (see header comment).  4 waves (2x2),
// each wave 64x64 (MI=4, NI=4, 32 MFMA/iter).  2-buffer LDS (64KB), CPT=8.
// Phase A: ds_read 16x b128 -> regs (while tile kk+1 DMA in flight).
// Phase B: stage(kk+2) into just-freed buf, then pure-reg MFMA cluster.
// ---------------------------------------------------------------------------
template <int KK, int EPI>
__global__ __launch_bounds__(256) void gemm2p(
    const ushort* __restrict__ A, int lda,
    const ushort* __restrict__ Bt, int N,
    const float* __restrict__ bias,
    const ushort* __restrict__ tcb, int tcld,
    float* __restrict__ s_arr,
    void* __restrict__ Cout, int ldc)
{
    constexpr int TM = 128, TN = 128;
    constexpr int MI = 4, NI = 4;
    constexpr int ROWS = 256;
    constexpr int CPT = 8;                      // (256 rows * 8 chunks)/256 thr
    constexpr int MT = 128, MT_PER_BAND = 16;
    constexpr int NK = KK >> 6;
    static_assert(NK >= 2, "pipeline needs >=2 K-iters");
    __shared__ ushort S[2 * ROWS * 64];         // 64 KB -> 2 blocks/CU

    const int g = blockIdx.x;
    const int band = g & 7, within = g >> 3;
    const int nt = within / MT_PER_BAND;
    const int mt = band * MT_PER_BAND + (within - nt * MT_PER_BAND);
    const int m0 = mt * TM, n0 = nt * TN;
    const int w = threadIdx.x >> 6, L = threadIdx.x & 63;
    const int wr0 = (w >> 1) * 64, wc0 = (w & 1) * 64;
    const int lrow = L & 15, quad = L >> 4;

    const ushort* gbase[CPT];
#pragma unroll
    for (int rr = 0; rr < CPT; ++rr) {
        const int chunk = rr * 256 + (w << 6) + L;
        const int row = chunk >> 3, slot = chunk & 7;
        const int ca = slot ^ ((row >> 1) & 7);
        gbase[rr] = (row < TM)
            ? A  + (size_t)(m0 + row) * lda    + (ca << 3)
            : Bt + (size_t)(n0 + row - TM) * KK + (ca << 3);
    }

    floatx4 zero4 = {0.0f, 0.0f, 0.0f, 0.0f};
    floatx4 acc[MI][NI];
#pragma unroll
    for (int i = 0; i < MI; ++i)
#pragma unroll
        for (int j = 0; j < NI; ++j) acc[i][j] = zero4;

    auto stage = [&](int buf, int k0) {
        ushort* Sd = S + buf * (ROWS * 64);
#pragma unroll
        for (int rr = 0; rr < CPT; ++rr) {
            __builtin_amdgcn_global_load_lds(
                (const __attribute__((address_space(1))) unsigned int*)(gbase[rr] + k0),
                (__attribute__((address_space(3))) unsigned int*)(Sd + (rr * 256 + (w << 6)) * 8),
                16, 0, 0);
        }
    };

    stage(0, 0);                                 // tiles 0,1 in flight (16)
    stage(1, 64);
#pragma unroll
    for (int kk = 0; kk < NK; ++kk) {
        // A: own tile-kk DMAs retired (tile kk+1 stays in flight); barrier
        //    -> ALL waves' tile kk landed in LDS.
        if (kk + 1 < NK)
            asm volatile("s_waitcnt vmcnt(8) lgkmcnt(0)" ::: "memory");
        else
            asm volatile("s_waitcnt vmcnt(0) lgkmcnt(0)" ::: "memory");
        __builtin_amdgcn_s_barrier();
        __builtin_amdgcn_sched_barrier(0);

        const ushort* Sc = S + (kk & 1) * (ROWS * 64);
        short8 af[2][MI], bfr[2][NI];
#pragma unroll
        for (int ks = 0; ks < 2; ++ks) {
#pragma unroll
            for (int mi = 0; mi < MI; ++mi) {
                const int row = wr0 + (mi << 4) + lrow;
                const int slot = ((ks << 2) + quad) ^ ((row >> 1) & 7);
                af[ks][mi] = *(const short8*)(Sc + row * 64 + (slot << 3));
            }
#pragma unroll
            for (int ni = 0; ni < NI; ++ni) {
                const int row = TM + wc0 + (ni << 4) + lrow;
                const int slot = ((ks << 2) + quad) ^ ((row >> 1) & 7);
                bfr[ks][ni] = *(const short8*)(Sc + row * 64 + (slot << 3));
            }
        }
        // B: own reads in regs; barrier -> ALL waves' reads done; then the
        //    stage for tile kk+2 may overwrite this buffer (WAR released).
        asm volatile("s_waitcnt lgkmcnt(0)" ::: "memory");
        __builtin_amdgcn_sched_barrier(0);
        __builtin_amdgcn_s_barrier();
        __builtin_amdgcn_sched_barrier(0);
        if (kk + 2 < NK) stage(kk & 1, (kk + 2) << 6);

        __builtin_amdgcn_s_setprio(1);
#pragma unroll
        for (int ks = 0; ks < 2; ++ks)
#pragma unroll
            for (int mi = 0; mi < MI; ++mi)
#pragma unroll
                for (int ni = 0; ni < NI; ++ni)
                    acc[mi][ni] = __builtin_amdgcn_mfma_f32_16x16x32_bf16(
                        bfr[ks][ni], af[ks][mi], acc[mi][ni], 0, 0, 0);
        __builtin_amdgcn_s_setprio(0);
    }

    // Swapped C/D layout: row gr, 4 consecutive cols gcb..+3.
    if constexpr (EPI == 3) {
#pragma unroll
        for (int mi = 0; mi < MI; ++mi) {
            const int gr = m0 + wr0 + (mi << 4) + lrow;
            float rs = 0.0f;
#pragma unroll
            for (int ni = 0; ni < NI; ++ni) {
                const int gcb = n0 + wc0 + (ni << 4) + (quad << 2);
                ushort4v t4 = *(const ushort4v*)(tcb + (size_t)gr * tcld + gcb);
#pragma unroll
                for (int p = 0; p < 4; ++p) rs += acc[mi][ni][p] * bf2f(t4[p]);
            }
            rs += __shfl_xor(rs, 16);
            rs += __shfl_xor(rs, 32);
            if (quad == 0) atomicAdd(s_arr + gr, rs);
        }
    } else {
#pragma unroll
        for (int mi = 0; mi < MI; ++mi) {
            const int gr = m0 + wr0 + (mi << 4) + lrow;
#pragma unroll
            for (int ni = 0; ni < NI; ++ni) {
                const int gcb = n0 + wc0 + (ni << 4) + (quad << 2);
                const floatx4 v = acc[mi][ni];
                if constexpr (EPI == 0) {
                    float4 bv = *(const float4*)(bias + gcb);
                    float4 o = {v[0] + bv.x, v[1] + bv.y, v[2] + bv.z, v[3] + bv.w};
                    *(float4*)((float*)Cout + (size_t)gr * ldc + gcb) = o;
                } else {   // EPI == 1
                    float4 bv = *(const float4*)(bias + gcb);
                    ushort4v o;
                    o[0] = f2bf(tanh_fast(v[0] + bv.x));
                    o[1] = f2bf(tanh_fast(v[1] + bv.y));
                    o[2] = f2bf(tanh_fast(v[2] + bv.z));
                    o[3] = f2bf(tanh_fast(v[3] + bv.w));
                    *(ushort4v*)((ushort*)Cout + (size_t)gr * ldc + gcb) = o;
                }
            }
        }
    }
}

// ---------------------------------------------------------------------------
// Prep: blocks [0,4096): xb = bf16(x) + fdot[r] = x[r].fiw  (one wave/row)
//       blocks [4096,5440): weight transposes fp32[K][N] -> bf16[N][K]
//       block 5440: bias concat
//       blocks [5441,5457): zero the stats region
// ---------------------------------------------------------------------------
__global__ __launch_bounds__(256) void prep_k(
    const float* __restrict__ x, const float* __restrict__ fiw,
    ushort* __restrict__ xb, float* __restrict__ fdot,
    const float* __restrict__ tp_w, const float* __restrict__ tc_w,
    const float* __restrict__ bilw, const float* __restrict__ ow,
    const float* __restrict__ w0, const float* __restrict__ w1,
    const float* __restrict__ tp_b, const float* __restrict__ tc_b,
    ushort* __restrict__ tptcwT, ushort* __restrict__ bilwT,
    ushort* __restrict__ owT, ushort* __restrict__ w0T,
    ushort* __restrict__ w1T, float* __restrict__ bias2,
    float* __restrict__ zstats, int zcount)
{
    const int blk0 = blockIdx.x;
    if (blk0 < 4096) {
        const int wv = threadIdx.x >> 6, L = threadIdx.x & 63;
        const int r = (blk0 << 2) + wv;
        const float* xr = x + (size_t)r * DD;
        const int c0 = L << 3;
        float4 v0 = *(const float4*)(xr + c0);
        float4 v1 = *(const float4*)(xr + c0 + 4);
        float4 f0 = *(const float4*)(fiw + c0);
        float4 f1 = *(const float4*)(fiw + c0 + 4);
        float d = v0.x * f0.x + v0.y * f0.y + v0.z * f0.z + v0.w * f0.w
                + v1.x * f1.x + v1.y * f1.y + v1.z * f1.z + v1.w * f1.w;
        ushort8v o;
        o[0] = f2bf(v0.x); o[1] = f2bf(v0.y); o[2] = f2bf(v0.z); o[3] = f2bf(v0.w);
        o[4] = f2bf(v1.x); o[5] = f2bf(v1.y); o[6] = f2bf(v1.z); o[7] = f2bf(v1.w);
        *(ushort8v*)(xb + (size_t)r * DD + c0) = o;
#pragma unroll
        for (int off = 32; off > 0; off >>= 1) d += __shfl_xor(d, off);
        if (L == 0) fdot[r] = d;
        return;
    }
    if (blk0 >= 5441) {                       // zero stats region
        for (int i = (blk0 - 5441) * 256 + threadIdx.x; i < zcount; i += 16 * 256)
            zstats[i] = 0.0f;
        return;
    }
    const int blk = blk0 - 4096;
    if (blk >= 1344) {
        for (int i = threadIdx.x; i < 512; i += 256) {
            bias2[i] = tp_b[i];
            bias2[512 + i] = tc_b[i];
        }
        return;
    }
    const float* W; ushort* Wt; int K, N, local;
    if (blk < 256)       { W = tp_w; Wt = tptcwT;              K = 512; N = 512; local = blk; }
    else if (blk < 512)  { W = tc_w; Wt = tptcwT + 512 * 512;  K = 512; N = 512; local = blk - 256; }
    else if (blk < 768)  { W = bilw; Wt = bilwT;               K = 512; N = 512; local = blk - 512; }
    else if (blk < 1024) { W = ow;   Wt = owT;                 K = 512; N = 512; local = blk - 768; }
    else if (blk < 1152) { W = w0;   Wt = w0T;                 K = 512; N = 256; local = blk - 1024; }
    else                 { W = w1;   Wt = w1T;                 K = 768; N = 256; local = blk - 1152; }

    __shared__ float t[32][33];
    const int nb = N >> 5;
    const int kb = local / nb, nbb = local % nb;
    const int k0 = kb << 5, n0 = nbb << 5;
    const int c = threadIdx.x & 31, r = threadIdx.x >> 5;   // r 0..7
#pragma unroll
    for (int i = 0; i < 4; ++i)
        t[r + 8 * i][c] = W[(size_t)(k0 + r + 8 * i) * N + n0 + c];
    __syncthreads();
#pragma unroll
    for (int i = 0; i < 4; ++i)
        Wt[(size_t)(n0 + r + 8 * i) * K + k0 + c] = f2bf(t[c][r + 8 * i]);
}

// ---------------------------------------------------------------------------
// Per batch (block = 1024 threads = 1 batch): a=exp(s), f=exp(fdot),
// S=sum a, H=sum a*f (tree reduce, no atomics), denom = 2 - a*f/H.
// ---------------------------------------------------------------------------
__global__ __launch_bounds__(1024) void finalize_k(
    const float* __restrict__ s_arr, const float* __restrict__ fdot,
    float* __restrict__ a, float* __restrict__ f,
    float* __restrict__ Sb, float* __restrict__ Hb, float* __restrict__ den)
{
    __shared__ float redS[16], redH[16];
    __shared__ float Hsh;
    const int b = blockIdx.x, t = threadIdx.x;
    const int r = (b << 10) + t;
    const float av = __expf(s_arr[r]), fv = __expf(fdot[r]);
    a[r] = av; f[r] = fv;
    float s1 = av, s2 = av * fv;
#pragma unroll
    for (int o = 32; o > 0; o >>= 1) { s1 += __shfl_xor(s1, o); s2 += __shfl_xor(s2, o); }
    if ((t & 63) == 0) { redS[t >> 6] = s1; redH[t >> 6] = s2; }
    __syncthreads();
    if (t == 0) {
        float S = 0.f, H = 0.f;
        for (int i = 0; i < 16; ++i) { S += redS[i]; H += redH[i]; }
        Sb[b] = S; Hb[b] = H; Hsh = H;
    }
    __syncthreads();
    den[r] = 2.0f - av * fv * __builtin_amdgcn_rcpf(Hsh);
}

// ---------------------------------------------------------------------------
// Per batch: P[c] = sum_n a_n V[n,c]; Q[c] = sum_n a_n f_n V[n,c].  V is bf16.
// grid = 16 batches x 16 row-chunks(64); LDS-reduce then <=16-collider atomics.
// ---------------------------------------------------------------------------
__global__ __launch_bounds__(256) void batch_pq(
    const ushort* __restrict__ V, const float* __restrict__ a, const float* __restrict__ f,
    float* __restrict__ P, float* __restrict__ Q, int C)
{
    __shared__ float redP[256][4];
    __shared__ float redQ[256][4];
    const int b = blockIdx.x >> 4;
    const int chunk = blockIdx.x & 15;
    const int c4cnt = C >> 2;
    const int rg = 256 / c4cnt;
    const int c4 = threadIdx.x & (c4cnt - 1);
    const int sub = threadIdx.x / c4cnt;
    const ushort* Vb = V + (size_t)b * 1024 * C;
    const float* ab = a + (b << 10);
    const float* fb = f + (b << 10);
    const int n0 = chunk << 6;
    float4 p = {0, 0, 0, 0}, q = {0, 0, 0, 0};
    for (int n = n0 + sub; n < n0 + 64; n += rg) {
        const float av = ab[n], afv = av * fb[n];
        ushort4v u = *(const ushort4v*)(Vb + (size_t)n * C + (c4 << 2));
        float4 v = {bf2f(u[0]), bf2f(u[1]), bf2f(u[2]), bf2f(u[3])};
        p.x += av * v.x; p.y += av * v.y; p.z += av * v.z; p.w += av * v.w;
        q.x += afv * v.x; q.y += afv * v.y; q.z += afv * v.z; q.w += afv * v.w;
    }
    redP[threadIdx.x][0] = p.x; redP[threadIdx.x][1] = p.y;
    redP[threadIdx.x][2] = p.z; redP[threadIdx.x][3] = p.w;
    redQ[threadIdx.x][0] = q.x; redQ[threadIdx.x][1] = q.y;
    redQ[threadIdx.x][2] = q.z; redQ[threadIdx.x][3] = q.w;
    __syncthreads();
    if (sub == 0) {
        for (int s = 1; s < rg; ++s) {
            const int t2 = threadIdx.x + s * c4cnt;
            p.x += redP[t2][0]; p.y += redP[t2][1]; p.z += redP[t2][2]; p.w += redP[t2][3];
            q.x += redQ[t2][0]; q.y += redQ[t2][1]; q.z += redQ[t2][2]; q.w += redQ[t2][3];
        }
        float* Pp = P + b * C + (c4 << 2);
        float* Qp = Q + b * C + (c4 << 2);
        atomicAdd(Pp + 0, p.x); atomicAdd(Pp + 1, p.y);
        atomicAdd(Pp + 2, p.z); atomicAdd(Pp + 3, p.w);
        atomicAdd(Qp + 0, q.x); atomicAdd(Qp + 1, q.y);
        atomicAdd(Qp + 2, q.z); atomicAdd(Qp + 3, q.w);
    }
}

// ---------------------------------------------------------------------------
// h = adj@V + V (rank-3 + diagonal closed form), V bf16, bf16 store to
// outb[r][co..co+C) with row stride ldo.
// ---------------------------------------------------------------------------
__global__ __launch_bounds__(256) void mix_k(
    const ushort* __restrict__ V, const float* __restrict__ P, const float* __restrict__ Q,
    const float* __restrict__ a, const float* __restrict__ f,
    const float* __restrict__ Sb, const float* __restrict__ Hb,
    ushort* __restrict__ outb, int C, int ldo, int co)
{
    const int idx = blockIdx.x * 256 + threadIdx.x;
    const int c4c = C >> 2;
    const int r = idx / c4c, c4 = idx - r * c4c;
    const int b = r >> 10;
    const float av = a[r], fv = f[r], S = Sb[b], H = Hb[b];
    const float rS = __builtin_amdgcn_rcpf(S);
    const float beta = av * rS * __builtin_amdgcn_rcpf(H);
    const float alpha = 1.0f - av * rS;
    const float cp = rS - beta * fv;
    ushort4v u = *(const ushort4v*)(V + (size_t)r * C + (c4 << 2));
    float4 v = {bf2f(u[0]), bf2f(u[1]), bf2f(u[2]), bf2f(u[3])};
    const float* Pp = P + b * C + (c4 << 2);
    const float* Qp = Q + b * C + (c4 << 2);
    ushort4v o;
    o[0] = f2bf(alpha * v.x + cp * Pp[0] + beta * Qp[0]);
    o[1] = f2bf(alpha * v.y + cp * Pp[1] + beta * Qp[1]);
    o[2] = f2bf(alpha * v.z + cp * Pp[2] + beta * Qp[2]);
    o[3] = f2bf(alpha * v.w + cp * Pp[3] + beta * Qp[3]);
    *(ushort4v*)(outb + (size_t)r * ldo + co + (c4 << 2)) = o;
}

extern "C" void kernel_launch(void* const* d_in, const int* in_sizes, int n_in,
                              void* d_out, int out_size, void* d_ws, size_t ws_size,
                              hipStream_t stream)
{
    (void)in_sizes; (void)n_in; (void)out_size; (void)ws_size;
    const float* x    = (const float*)d_in[0];
    const float* tp_w = (const float*)d_in[1];
    const float* tp_b = (const float*)d_in[2];
    const float* tc_w = (const float*)d_in[3];
    const float* tc_b = (const float*)d_in[4];
    const float* fi_w = (const float*)d_in[5];
    const float* bilw = (const float*)d_in[6];
    const float* w0   = (const float*)d_in[7];
    const float* b0   = (const float*)d_in[8];
    const float* w1   = (const float*)d_in[9];
    const float* b1   = (const float*)d_in[10];
    const float* ow   = (const float*)d_in[11];
    const float* ob   = (const float*)d_in[12];

    char* W = (char*)d_ws;
    ushort* xb    = (ushort*)W;                          // [0,16M)  xb -> gcnb overlay
    ushort* gcnb  = xb;
    ushort* tptcb = (ushort*)(W + ((size_t)16 << 20));   // [16M,48M) 32MB; dies after s-GEMM
    ushort* Hbuf  = tptcb;                               // [16M,40M) 24MB overlay: [h0|hg] ld 768
    ushort* g0b   = (ushort*)(W + ((size_t)48 << 20));   // 8MB
    ushort* tptcwT= (ushort*)(W + ((size_t)56 << 20));   // 1024x512
    ushort* bilwT = tptcwT + 524288;                     // 512x512
    ushort* owT   = bilwT + 262144;                      // 512x512
    ushort* w0T   = owT + 262144;                        // 256x512
    ushort* w1T   = w0T + 131072;                        // 256x768
    float*  bias2 = (float*)(w1T + 196608);              // 1024
    float* stats  = (float*)(W + ((size_t)60 << 20));
    float* s_arr  = stats;             // 16384
    float* P0     = s_arr + 16384;     // 8192
    float* Q0     = P0 + 8192;         // 8192
    float* P1     = Q0 + 8192;         // 4096
    float* Q1     = P1 + 4096;         // 4096
    const int zcount = 16384 + 2 * 8192 + 2 * 4096;
    float* fdot   = Q1 + 4096;
    float* arr_a  = fdot + BN;
    float* arr_f  = arr_a + BN;
    float* arr_den= arr_f + BN;
    float* Sb     = arr_den + BN;
    float* Hb     = Sb + 16;

    // prep: xb=bf16(x), fdot, weight transposes, bias concat, stats zeroing
    prep_k<<<5457, 256, 0, stream>>>(x, fi_w, xb, fdot, tp_w, tc_w, bilw, ow, w0, w1,
                                     tp_b, tc_b, tptcwT, bilwT, owT, w0T, w1T, bias2,
                                     s_arr, zcount);
    // G1: [tp|tc] = tanh(x@[tpw|tcw] + [tpb|tcb])  (2-phase 128x128)
    // grid = 128 * (1024/128) = 1024 blocks
    gemm2p<512, 1><<<1024, 256, 0, stream>>>(xb, 512, tptcwT, 1024, bias2,
        nullptr, 0, nullptr, tptcb, 1024);
    // G2: s[r] = (tp@bilw)[r] . tc[r]  (2-phase; grid = 128*4 = 512)
    gemm2p<512, 3><<<512, 256, 0, stream>>>(tptcb, 1024, bilwT, 512, nullptr,
        tptcb + 512, 1024, s_arr, nullptr, 0);
    // a, f, S, H, denom
    finalize_k<<<16, 1024, 0, stream>>>(s_arr, fdot, arr_a, arr_f, Sb, Hb, arr_den);
    // layer 0: h0 = adj@x + x -> Hbuf[:, 0:512] bf16
    batch_pq<<<256, 256, 0, stream>>>(xb, arr_a, arr_f, P0, Q0, 512);
    mix_k<<<8192, 256, 0, stream>>>(xb, P0, Q0, arr_a, arr_f, Sb, Hb, Hbuf, 512, 768, 0);
    // G3: g0 = relu((h0@W0 + 2 b0)/den)  (R4 128x64 3-buffer, grid 512)
    gemm_lds<128, 64, 512, 2><<<512, 256, 0, stream>>>(Hbuf, 768, w0T, 256, b0,
        arr_den, nullptr, 0, nullptr, g0b, 256, xb, 0, gcnb);
    // layer 1: hg = adj@g0 + g0 -> Hbuf[:, 512:768] bf16
    batch_pq<<<256, 256, 0, stream>>>(g0b, arr_a, arr_f, P1, Q1, 256);
    mix_k<<<4096, 256, 0, stream>>>(g0b, P1, Q1, arr_a, arr_f, Sb, Hb, Hbuf, 256, 768, 512);
    // G4: g1 = relu(([h0|hg]@W1 + 2 b1)/den)  (R4 128x64 3-buffer, grid 512)
    gemm_lds<128, 64, 768, 2><<<512, 256, 0, stream>>>(Hbuf, 768, w1T, 256, b1,
        arr_den, nullptr, 0, nullptr, nullptr, 0, xb, 256, gcnb);
    // G5: out = gcn@out_w + out_b  (2-phase; grid = 128*4 = 512)
    gemm2p<512, 0><<<512, 256, 0, stream>>>(gcnb, 512, owT, 512, ob,
        nullptr, 0, nullptr, (float*)d_out, 512);
}